// Round 1
// baseline (13372.197 us; speedup 1.0000x reference)
//
#include <hip/hip_runtime.h>
#include <hip/hip_bf16.h>

#define N_NODES 100000
#define N_EDGES 600000
#define D 128
#define NPG 1000
#define NGRAPH 100

typedef unsigned short u16;
typedef unsigned int u32;

__device__ __forceinline__ float bf2f(u16 u) {
  return __uint_as_float(((u32)u) << 16);
}
__device__ __forceinline__ u16 f2bf(float f) {
  u32 u = __float_as_uint(f);
  u32 r = (u + 0x7FFFu + ((u >> 16) & 1u)) >> 16;  // round-to-nearest-even
  return (u16)r;
}
__device__ __forceinline__ void fma4(float4& acc, float a, const float4 w) {
  acc.x = fmaf(a, w.x, acc.x);
  acc.y = fmaf(a, w.y, acc.y);
  acc.z = fmaf(a, w.z, acc.z);
  acc.w = fmaf(a, w.w, acc.w);
}

// x[n][d] = embedding[tok[n]][d]
__global__ __launch_bounds__(256) void k_embed(const int* __restrict__ tok,
                                               const float* __restrict__ emb,
                                               float* __restrict__ x) {
  int t = blockIdx.x * 256 + threadIdx.x;
  if (t >= N_NODES * 32) return;
  int node = t >> 5, q = t & 31;
  const float4* s = (const float4*)(emb + (size_t)tok[node] * D);
  ((float4*)(x + (size_t)node * D))[q] = s[q];
}

// ea[e][d] = edge_attr[e][:16] @ w_proj + b_proj  (stored bf16)
__global__ __launch_bounds__(256) void k_proj(const float* __restrict__ attr,
                                              const float* __restrict__ w,
                                              const float* __restrict__ b,
                                              u16* __restrict__ ea) {
  int t = blockIdx.x * 256 + threadIdx.x;
  if (t >= N_EDGES * 128) return;  // 76.8M < 2^31
  int e = t >> 7, d = t & 127;
  const float* a = attr + (size_t)e * 16;
  float acc = b[d];
#pragma unroll
  for (int k = 0; k < 16; ++k) acc = fmaf(a[k], w[k * D + d], acc);
  ea[(size_t)e * D + d] = f2bf(acc);
}

// xout[n] = xin[n] @ w + b   (prune!=0: only master nodes n%NPG==0)
__global__ __launch_bounds__(256) void k_self(const float* __restrict__ xin,
                                              const float* __restrict__ w,
                                              const float* __restrict__ b,
                                              float* __restrict__ xout, int prune) {
  int t = blockIdx.x * 256 + threadIdx.x;
  int node = t >> 5;
  if (node >= N_NODES) return;
  int q = t & 31;
  if (prune && (node % NPG)) return;
  const float4* xr = (const float4*)(xin + (size_t)node * D);
  const float4* w4 = (const float4*)w;
  float4 acc = ((const float4*)b)[q];
#pragma unroll 4
  for (int k4 = 0; k4 < 32; ++k4) {
    float4 xv = xr[k4];
    fma4(acc, xv.x, w4[(k4 * 4 + 0) * 32 + q]);
    fma4(acc, xv.y, w4[(k4 * 4 + 1) * 32 + q]);
    fma4(acc, xv.z, w4[(k4 * 4 + 2) * 32 + q]);
    fma4(acc, xv.w, w4[(k4 * 4 + 3) * 32 + q]);
  }
  ((float4*)(xout + (size_t)node * D))[q] = acc;
}

// msg = [x[src] | ea] @ w_msg + b_msg ; atomicAdd into xout[dst]
// prune!=0: only edges whose dst is a master node
__global__ __launch_bounds__(256) void k_msg(const float* __restrict__ x,
                                             const u16* __restrict__ ea,
                                             const int* __restrict__ src,
                                             const int* __restrict__ dst,
                                             const float* __restrict__ w,
                                             const float* __restrict__ b,
                                             float* __restrict__ xout, int prune) {
  int t = blockIdx.x * 256 + threadIdx.x;
  int e = t >> 5;
  if (e >= N_EDGES) return;
  int q = t & 31;
  int de = dst[e];
  if (prune && (de % NPG)) return;
  const float4* xs = (const float4*)(x + (size_t)src[e] * D);
  const uint4* er = (const uint4*)(ea + (size_t)e * D);
  const float4* w4 = (const float4*)w;
  float4 acc = ((const float4*)b)[q];
#pragma unroll 4
  for (int k4 = 0; k4 < 32; ++k4) {
    float4 xv = xs[k4];
    fma4(acc, xv.x, w4[(k4 * 4 + 0) * 32 + q]);
    fma4(acc, xv.y, w4[(k4 * 4 + 1) * 32 + q]);
    fma4(acc, xv.z, w4[(k4 * 4 + 2) * 32 + q]);
    fma4(acc, xv.w, w4[(k4 * 4 + 3) * 32 + q]);
  }
#pragma unroll 2
  for (int k8 = 0; k8 < 16; ++k8) {
    uint4 u = er[k8];
    u32 uu[4] = {u.x, u.y, u.z, u.w};
#pragma unroll
    for (int j = 0; j < 4; ++j) {
      float lo = bf2f((u16)(uu[j] & 0xFFFFu));
      float hi = bf2f((u16)(uu[j] >> 16));
      fma4(acc, lo, w4[(D + k8 * 8 + j * 2 + 0) * 32 + q]);
      fma4(acc, hi, w4[(D + k8 * 8 + j * 2 + 1) * 32 + q]);
    }
  }
  float* o = xout + (size_t)de * D + q * 4;
  atomicAdd(o + 0, acc.x);
  atomicAdd(o + 1, acc.y);
  atomicAdd(o + 2, acc.z);
  atomicAdd(o + 3, acc.w);
}

// ea[e] = act( [x[dst] | x[src] | ea[e]] @ w_edge + b_edge )  in-place (safe: all
// reads of this edge's row precede the write within the owning wave)
__global__ __launch_bounds__(256) void k_edge(const float* __restrict__ x,
                                              u16* __restrict__ ea,
                                              const int* __restrict__ src,
                                              const int* __restrict__ dst,
                                              const float* __restrict__ w,
                                              const float* __restrict__ b,
                                              int relu) {
  int t = blockIdx.x * 256 + threadIdx.x;
  int e = t >> 5;
  if (e >= N_EDGES) return;
  int q = t & 31;
  const float4* xi = (const float4*)(x + (size_t)dst[e] * D);
  const float4* xj = (const float4*)(x + (size_t)src[e] * D);
  uint4* er = (uint4*)(ea + (size_t)e * D);
  const float4* w4 = (const float4*)w;
  float4 acc = ((const float4*)b)[q];
#pragma unroll 4
  for (int k4 = 0; k4 < 32; ++k4) {  // xi rows 0..127
    float4 xv = xi[k4];
    fma4(acc, xv.x, w4[(k4 * 4 + 0) * 32 + q]);
    fma4(acc, xv.y, w4[(k4 * 4 + 1) * 32 + q]);
    fma4(acc, xv.z, w4[(k4 * 4 + 2) * 32 + q]);
    fma4(acc, xv.w, w4[(k4 * 4 + 3) * 32 + q]);
  }
#pragma unroll 4
  for (int k4 = 0; k4 < 32; ++k4) {  // xj rows 128..255
    float4 xv = xj[k4];
    fma4(acc, xv.x, w4[(D + k4 * 4 + 0) * 32 + q]);
    fma4(acc, xv.y, w4[(D + k4 * 4 + 1) * 32 + q]);
    fma4(acc, xv.z, w4[(D + k4 * 4 + 2) * 32 + q]);
    fma4(acc, xv.w, w4[(D + k4 * 4 + 3) * 32 + q]);
  }
#pragma unroll 2
  for (int k8 = 0; k8 < 16; ++k8) {  // ea rows 256..383
    uint4 u = ((const uint4*)er)[k8];
    u32 uu[4] = {u.x, u.y, u.z, u.w};
#pragma unroll
    for (int j = 0; j < 4; ++j) {
      float lo = bf2f((u16)(uu[j] & 0xFFFFu));
      float hi = bf2f((u16)(uu[j] >> 16));
      fma4(acc, lo, w4[(2 * D + k8 * 8 + j * 2 + 0) * 32 + q]);
      fma4(acc, hi, w4[(2 * D + k8 * 8 + j * 2 + 1) * 32 + q]);
    }
  }
  if (relu) {
    acc.x = fmaxf(acc.x, 0.f);
    acc.y = fmaxf(acc.y, 0.f);
    acc.z = fmaxf(acc.z, 0.f);
    acc.w = fmaxf(acc.w, 0.f);
  }
  u32 p0 = (u32)f2bf(acc.x) | ((u32)f2bf(acc.y) << 16);
  u32 p1 = (u32)f2bf(acc.z) | ((u32)f2bf(acc.w) << 16);
  ((uint2*)er)[q] = make_uint2(p0, p1);
}

__global__ __launch_bounds__(256) void k_relu(float* __restrict__ x) {
  int t = blockIdx.x * 256 + threadIdx.x;
  if (t >= N_NODES * 32) return;
  float4* p = (float4*)x + t;
  float4 v = *p;
  v.x = fmaxf(v.x, 0.f);
  v.y = fmaxf(v.y, 0.f);
  v.z = fmaxf(v.z, 0.f);
  v.w = fmaxf(v.w, 0.f);
  *p = v;
}

__global__ __launch_bounds__(256) void k_out(const float* __restrict__ x,
                                             float* __restrict__ out) {
  int t = blockIdx.x * 256 + threadIdx.x;
  if (t >= NGRAPH * 32) return;
  int g = t >> 5, q = t & 31;
  ((float4*)(out + (size_t)g * D))[q] = ((const float4*)(x + (size_t)g * NPG * D))[q];
}

extern "C" void kernel_launch(void* const* d_in, const int* in_sizes, int n_in,
                              void* d_out, int out_size, void* d_ws, size_t ws_size,
                              hipStream_t stream) {
  const int* tok = (const int*)d_in[0];
  const int* eidx = (const int*)d_in[1];
  const int* srcp = eidx;
  const int* dstp = eidx + N_EDGES;
  const float* attr = (const float*)d_in[2];
  // d_in[3] = batch (unused; master layout is n % NPG == 0)
  const float* emb = (const float*)d_in[4];
  const float* w_proj = (const float*)d_in[5];
  const float* b_proj = (const float*)d_in[6];
  const float *ws_[3], *bs_[3], *wm_[3], *bm_[3], *we_[3], *be_[3];
  for (int i = 0; i < 3; ++i) {
    ws_[i] = (const float*)d_in[7 + 6 * i];
    bs_[i] = (const float*)d_in[8 + 6 * i];
    wm_[i] = (const float*)d_in[9 + 6 * i];
    bm_[i] = (const float*)d_in[10 + 6 * i];
    we_[i] = (const float*)d_in[11 + 6 * i];
    be_[i] = (const float*)d_in[12 + 6 * i];
  }
  float* out = (float*)d_out;

  float* xA = (float*)d_ws;                       // 51.2 MB
  float* xB = xA + (size_t)N_NODES * D;           // 51.2 MB
  u16* ea = (u16*)(xB + (size_t)N_NODES * D);     // 153.6 MB bf16

  const int NODE_G = (N_NODES * 32) / 256;        // 12500
  const int EDGE_G = (N_EDGES * 32) / 256;        // 75000
  const int PROJ_G = (N_EDGES * 128) / 256;       // 300000
  dim3 B(256);

  k_embed<<<NODE_G, B, 0, stream>>>(tok, emb, xA);
  k_proj<<<PROJ_G, B, 0, stream>>>(attr, w_proj, b_proj, ea);

  // layer 1: x = xA -> xB
  k_self<<<NODE_G, B, 0, stream>>>(xA, ws_[0], bs_[0], xB, 0);
  k_msg<<<EDGE_G, B, 0, stream>>>(xA, ea, srcp, dstp, wm_[0], bm_[0], xB, 0);
  k_edge<<<EDGE_G, B, 0, stream>>>(xA, ea, srcp, dstp, we_[0], be_[0], 1);
  k_relu<<<NODE_G, B, 0, stream>>>(xB);

  // layer 2: x = xB -> xA
  k_self<<<NODE_G, B, 0, stream>>>(xB, ws_[1], bs_[1], xA, 0);
  k_msg<<<EDGE_G, B, 0, stream>>>(xB, ea, srcp, dstp, wm_[1], bm_[1], xA, 0);
  k_edge<<<EDGE_G, B, 0, stream>>>(xB, ea, srcp, dstp, we_[1], be_[1], 1);
  k_relu<<<NODE_G, B, 0, stream>>>(xA);

  // layer 3: only master nodes are ever read; e_out3 is discarded entirely
  k_self<<<NODE_G, B, 0, stream>>>(xA, ws_[2], bs_[2], xB, 1);
  k_msg<<<EDGE_G, B, 0, stream>>>(xA, ea, srcp, dstp, wm_[2], bm_[2], xB, 1);

  k_out<<<13, B, 0, stream>>>(xB, out);
}

// Round 2
// 510.878 us; speedup vs baseline: 26.1749x; 26.1749x over previous
//
#include <hip/hip_runtime.h>

typedef unsigned short u16;
typedef unsigned int u32;
typedef unsigned char u8;

#define N_NODES 100000
#define N_EDGES 600000
#define D 128
#define NPG 1000
#define NGRAPH 100

// capacities for compacted lists (expected: E1~29k, E2~4.2k, E3~600)
#define CAP1 131072
#define CAP2 32768
#define CAP3 8192

// counter slots
#define C_E3 0
#define C_E2 1
#define C_E1 2
#define C_L0 3
#define C_L1 4
#define C_L2 5

__device__ __forceinline__ float bf2f(u16 u) {
  return __uint_as_float(((u32)u) << 16);
}
__device__ __forceinline__ u16 f2bf(float f) {
  u32 u = __float_as_uint(f);
  u32 r = (u + 0x7FFFu + ((u >> 16) & 1u)) >> 16;  // round-to-nearest-even
  return (u16)r;
}
__device__ __forceinline__ void fma4(float4& acc, float a, const float4 w) {
  acc.x = fmaf(a, w.x, acc.x);
  acc.y = fmaf(a, w.y, acc.y);
  acc.z = fmaf(a, w.z, acc.z);
  acc.w = fmaf(a, w.w, acc.w);
}

// ---------------- dependency-cone scans ----------------

__global__ __launch_bounds__(256) void k_mark_masters(u8* __restrict__ m2) {
  int t = blockIdx.x * 256 + threadIdx.x;
  if (t < NGRAPH) m2[t * NPG] = 1;
}

// E3 = edges into masters; m2 |= src(E3)
__global__ __launch_bounds__(256) void k_scan3(const int* __restrict__ src,
                                               const int* __restrict__ dst,
                                               u8* __restrict__ m2,
                                               int* __restrict__ E3,
                                               int* __restrict__ ctrl) {
  int e = blockIdx.x * 256 + threadIdx.x;
  if (e >= N_EDGES) return;
  if (dst[e] % NPG == 0) {
    int p = atomicAdd(&ctrl[C_E3], 1);
    if (p < CAP3) E3[p] = e;
    m2[src[e]] = 1;
  }
}

// E2 = edges into m2 nodes; m1 gets src(E2)
__global__ __launch_bounds__(256) void k_scan2(const int* __restrict__ src,
                                               const int* __restrict__ dst,
                                               const u8* __restrict__ m2,
                                               u8* __restrict__ m1,
                                               int* __restrict__ E2,
                                               int* __restrict__ ctrl) {
  int e = blockIdx.x * 256 + threadIdx.x;
  if (e >= N_EDGES) return;
  if (m2[dst[e]]) {
    int p = atomicAdd(&ctrl[C_E2], 1);
    if (p < CAP2) E2[p] = e;
    m1[src[e]] = 1;
  }
}

// E1 = edges into m1 nodes; emap[e] = slot in compacted ea buffer; m0 gets src(E1)
__global__ __launch_bounds__(256) void k_scan1(const int* __restrict__ src,
                                               const int* __restrict__ dst,
                                               const u8* __restrict__ m1,
                                               u8* __restrict__ m0,
                                               int* __restrict__ E1,
                                               int* __restrict__ emap,
                                               int* __restrict__ ctrl) {
  int e = blockIdx.x * 256 + threadIdx.x;
  if (e >= N_EDGES) return;
  if (m1[dst[e]]) {
    int p = atomicAdd(&ctrl[C_E1], 1);
    if (p < CAP1) {
      E1[p] = e;
      emap[e] = p;
    }
    m0[src[e]] = 1;
  }
}

__global__ __launch_bounds__(256) void k_or_mask(u8* __restrict__ dstm,
                                                 const u8* __restrict__ srcm) {
  int t = blockIdx.x * 256 + threadIdx.x;
  if (t < N_NODES && srcm[t]) dstm[t] = 1;
}

__global__ __launch_bounds__(256) void k_compact(const u8* __restrict__ m,
                                                 int* __restrict__ L,
                                                 int* __restrict__ ctrl, int slot) {
  int t = blockIdx.x * 256 + threadIdx.x;
  if (t < N_NODES && m[t]) {
    int p = atomicAdd(&ctrl[slot], 1);
    L[p] = t;
  }
}

// ---------------- compute kernels (grid-stride over device counts) ----------------

// x[node] = embedding[tok[node]]  for node in L
__global__ __launch_bounds__(256) void k_embed_l(const int* __restrict__ tok,
                                                 const float* __restrict__ emb,
                                                 float* __restrict__ x,
                                                 const int* __restrict__ L,
                                                 const int* __restrict__ ctrl, int slot) {
  int n = ctrl[slot];
  int sub = threadIdx.x >> 5, q = threadIdx.x & 31;
  for (int i = blockIdx.x * 8 + sub; i < n; i += gridDim.x * 8) {
    int node = L[i];
    const float4* s = (const float4*)(emb + (size_t)tok[node] * D);
    ((float4*)(x + (size_t)node * D))[q] = s[q];
  }
}

// ea_c[i] = edge_attr[E1[i]] @ w_proj + b_proj (bf16), slot i == position in E1
__global__ __launch_bounds__(256) void k_proj_l(const float* __restrict__ attr,
                                                const float* __restrict__ w,
                                                const float* __restrict__ b,
                                                u16* __restrict__ ea,
                                                const int* __restrict__ E1,
                                                const int* __restrict__ ctrl) {
  int n = ctrl[C_E1];
  int sub = threadIdx.x >> 7, d = threadIdx.x & 127;
  for (int i = blockIdx.x * 2 + sub; i < n; i += gridDim.x * 2) {
    int e = E1[i];
    const float* a = attr + (size_t)e * 16;
    float acc = b[d];
#pragma unroll
    for (int k = 0; k < 16; ++k) acc = fmaf(a[k], w[k * D + d], acc);
    ea[(size_t)i * D + d] = f2bf(acc);
  }
}

// xout[node] = xin[node] @ w + b  for node in L  (write, not add)
__global__ __launch_bounds__(256) void k_self_l(const float* __restrict__ xin,
                                                const float* __restrict__ w,
                                                const float* __restrict__ b,
                                                float* __restrict__ xout,
                                                const int* __restrict__ L,
                                                const int* __restrict__ ctrl, int slot) {
  int n = ctrl[slot];
  int sub = threadIdx.x >> 5, q = threadIdx.x & 31;
  const float4* w4 = (const float4*)w;
  for (int i = blockIdx.x * 8 + sub; i < n; i += gridDim.x * 8) {
    int node = L[i];
    const float4* xr = (const float4*)(xin + (size_t)node * D);
    float4 acc = ((const float4*)b)[q];
#pragma unroll 4
    for (int k4 = 0; k4 < 32; ++k4) {
      float4 xv = xr[k4];
      fma4(acc, xv.x, w4[(k4 * 4 + 0) * 32 + q]);
      fma4(acc, xv.y, w4[(k4 * 4 + 1) * 32 + q]);
      fma4(acc, xv.z, w4[(k4 * 4 + 2) * 32 + q]);
      fma4(acc, xv.w, w4[(k4 * 4 + 3) * 32 + q]);
    }
    ((float4*)(xout + (size_t)node * D))[q] = acc;
  }
}

// xout[dst[e]] += [x[src[e]] | ea_c[emap[e]]] @ w_msg + b_msg   for e in elist
__global__ __launch_bounds__(256) void k_msg_l(const float* __restrict__ x,
                                               const u16* __restrict__ ea,
                                               const int* __restrict__ src,
                                               const int* __restrict__ dst,
                                               const int* __restrict__ emap,
                                               const float* __restrict__ w,
                                               const float* __restrict__ b,
                                               float* __restrict__ xout,
                                               const int* __restrict__ elist,
                                               const int* __restrict__ ctrl, int slot) {
  int n = ctrl[slot];
  int sub = threadIdx.x >> 5, q = threadIdx.x & 31;
  const float4* w4 = (const float4*)w;
  for (int i = blockIdx.x * 8 + sub; i < n; i += gridDim.x * 8) {
    int e = elist[i];
    int sl = emap[e];
    const float4* xs = (const float4*)(x + (size_t)src[e] * D);
    const uint4* er = (const uint4*)(ea + (size_t)sl * D);
    float4 acc = ((const float4*)b)[q];
#pragma unroll 4
    for (int k4 = 0; k4 < 32; ++k4) {
      float4 xv = xs[k4];
      fma4(acc, xv.x, w4[(k4 * 4 + 0) * 32 + q]);
      fma4(acc, xv.y, w4[(k4 * 4 + 1) * 32 + q]);
      fma4(acc, xv.z, w4[(k4 * 4 + 2) * 32 + q]);
      fma4(acc, xv.w, w4[(k4 * 4 + 3) * 32 + q]);
    }
#pragma unroll 2
    for (int k8 = 0; k8 < 16; ++k8) {
      uint4 u = er[k8];
      u32 uu[4] = {u.x, u.y, u.z, u.w};
#pragma unroll
      for (int j = 0; j < 4; ++j) {
        float lo = bf2f((u16)(uu[j] & 0xFFFFu));
        float hi = bf2f((u16)(uu[j] >> 16));
        fma4(acc, lo, w4[(D + k8 * 8 + j * 2 + 0) * 32 + q]);
        fma4(acc, hi, w4[(D + k8 * 8 + j * 2 + 1) * 32 + q]);
      }
    }
    float* o = xout + (size_t)dst[e] * D + q * 4;
    atomicAdd(o + 0, acc.x);
    atomicAdd(o + 1, acc.y);
    atomicAdd(o + 2, acc.z);
    atomicAdd(o + 3, acc.w);
  }
}

// final-layer msg: accumulate into out[(dst/NPG)*D + ...]
__global__ __launch_bounds__(256) void k_msg3(const float* __restrict__ x,
                                              const u16* __restrict__ ea,
                                              const int* __restrict__ src,
                                              const int* __restrict__ dst,
                                              const int* __restrict__ emap,
                                              const float* __restrict__ w,
                                              const float* __restrict__ b,
                                              float* __restrict__ out,
                                              const int* __restrict__ elist,
                                              const int* __restrict__ ctrl) {
  int n = ctrl[C_E3];
  int sub = threadIdx.x >> 5, q = threadIdx.x & 31;
  const float4* w4 = (const float4*)w;
  for (int i = blockIdx.x * 8 + sub; i < n; i += gridDim.x * 8) {
    int e = elist[i];
    int sl = emap[e];
    const float4* xs = (const float4*)(x + (size_t)src[e] * D);
    const uint4* er = (const uint4*)(ea + (size_t)sl * D);
    float4 acc = ((const float4*)b)[q];
#pragma unroll 4
    for (int k4 = 0; k4 < 32; ++k4) {
      float4 xv = xs[k4];
      fma4(acc, xv.x, w4[(k4 * 4 + 0) * 32 + q]);
      fma4(acc, xv.y, w4[(k4 * 4 + 1) * 32 + q]);
      fma4(acc, xv.z, w4[(k4 * 4 + 2) * 32 + q]);
      fma4(acc, xv.w, w4[(k4 * 4 + 3) * 32 + q]);
    }
#pragma unroll 2
    for (int k8 = 0; k8 < 16; ++k8) {
      uint4 u = er[k8];
      u32 uu[4] = {u.x, u.y, u.z, u.w};
#pragma unroll
      for (int j = 0; j < 4; ++j) {
        float lo = bf2f((u16)(uu[j] & 0xFFFFu));
        float hi = bf2f((u16)(uu[j] >> 16));
        fma4(acc, lo, w4[(D + k8 * 8 + j * 2 + 0) * 32 + q]);
        fma4(acc, hi, w4[(D + k8 * 8 + j * 2 + 1) * 32 + q]);
      }
    }
    float* o = out + (size_t)(dst[e] / NPG) * D + q * 4;
    atomicAdd(o + 0, acc.x);
    atomicAdd(o + 1, acc.y);
    atomicAdd(o + 2, acc.z);
    atomicAdd(o + 3, acc.w);
  }
}

// ea_c[emap[e]] = relu([x[dst] | x[src] | ea_c[emap[e]]] @ w_edge + b_edge)  in place
__global__ __launch_bounds__(256) void k_edge_l(const float* __restrict__ x,
                                                u16* __restrict__ ea,
                                                const int* __restrict__ src,
                                                const int* __restrict__ dst,
                                                const int* __restrict__ emap,
                                                const float* __restrict__ w,
                                                const float* __restrict__ b,
                                                const int* __restrict__ elist,
                                                const int* __restrict__ ctrl, int slot) {
  int n = ctrl[slot];
  int sub = threadIdx.x >> 5, q = threadIdx.x & 31;
  const float4* w4 = (const float4*)w;
  for (int i = blockIdx.x * 8 + sub; i < n; i += gridDim.x * 8) {
    int e = elist[i];
    int sl = emap[e];
    const float4* xi = (const float4*)(x + (size_t)dst[e] * D);
    const float4* xj = (const float4*)(x + (size_t)src[e] * D);
    uint4* er = (uint4*)(ea + (size_t)sl * D);
    float4 acc = ((const float4*)b)[q];
#pragma unroll 4
    for (int k4 = 0; k4 < 32; ++k4) {
      float4 xv = xi[k4];
      fma4(acc, xv.x, w4[(k4 * 4 + 0) * 32 + q]);
      fma4(acc, xv.y, w4[(k4 * 4 + 1) * 32 + q]);
      fma4(acc, xv.z, w4[(k4 * 4 + 2) * 32 + q]);
      fma4(acc, xv.w, w4[(k4 * 4 + 3) * 32 + q]);
    }
#pragma unroll 4
    for (int k4 = 0; k4 < 32; ++k4) {
      float4 xv = xj[k4];
      fma4(acc, xv.x, w4[(D + k4 * 4 + 0) * 32 + q]);
      fma4(acc, xv.y, w4[(D + k4 * 4 + 1) * 32 + q]);
      fma4(acc, xv.z, w4[(D + k4 * 4 + 2) * 32 + q]);
      fma4(acc, xv.w, w4[(D + k4 * 4 + 3) * 32 + q]);
    }
#pragma unroll 2
    for (int k8 = 0; k8 < 16; ++k8) {
      uint4 u = ((const uint4*)er)[k8];
      u32 uu[4] = {u.x, u.y, u.z, u.w};
#pragma unroll
      for (int j = 0; j < 4; ++j) {
        float lo = bf2f((u16)(uu[j] & 0xFFFFu));
        float hi = bf2f((u16)(uu[j] >> 16));
        fma4(acc, lo, w4[(2 * D + k8 * 8 + j * 2 + 0) * 32 + q]);
        fma4(acc, hi, w4[(2 * D + k8 * 8 + j * 2 + 1) * 32 + q]);
      }
    }
    acc.x = fmaxf(acc.x, 0.f);
    acc.y = fmaxf(acc.y, 0.f);
    acc.z = fmaxf(acc.z, 0.f);
    acc.w = fmaxf(acc.w, 0.f);
    u32 p0 = (u32)f2bf(acc.x) | ((u32)f2bf(acc.y) << 16);
    u32 p1 = (u32)f2bf(acc.z) | ((u32)f2bf(acc.w) << 16);
    ((uint2*)er)[q] = make_uint2(p0, p1);
  }
}

__global__ __launch_bounds__(256) void k_relu_l(float* __restrict__ x,
                                                const int* __restrict__ L,
                                                const int* __restrict__ ctrl, int slot) {
  int n = ctrl[slot];
  int sub = threadIdx.x >> 5, q = threadIdx.x & 31;
  for (int i = blockIdx.x * 8 + sub; i < n; i += gridDim.x * 8) {
    float4* p = (float4*)(x + (size_t)L[i] * D) + q;
    float4 v = *p;
    v.x = fmaxf(v.x, 0.f);
    v.y = fmaxf(v.y, 0.f);
    v.z = fmaxf(v.z, 0.f);
    v.w = fmaxf(v.w, 0.f);
    *p = v;
  }
}

// out[g] = x[g*NPG] @ w + b  (write; masters statically known)
__global__ __launch_bounds__(256) void k_self3(const float* __restrict__ xin,
                                               const float* __restrict__ w,
                                               const float* __restrict__ b,
                                               float* __restrict__ out) {
  int t = blockIdx.x * 256 + threadIdx.x;
  if (t >= NGRAPH * 32) return;
  int g = t >> 5, q = t & 31;
  const float4* xr = (const float4*)(xin + (size_t)g * NPG * D);
  const float4* w4 = (const float4*)w;
  float4 acc = ((const float4*)b)[q];
#pragma unroll 4
  for (int k4 = 0; k4 < 32; ++k4) {
    float4 xv = xr[k4];
    fma4(acc, xv.x, w4[(k4 * 4 + 0) * 32 + q]);
    fma4(acc, xv.y, w4[(k4 * 4 + 1) * 32 + q]);
    fma4(acc, xv.z, w4[(k4 * 4 + 2) * 32 + q]);
    fma4(acc, xv.w, w4[(k4 * 4 + 3) * 32 + q]);
  }
  ((float4*)(out + (size_t)g * D))[q] = acc;
}

extern "C" void kernel_launch(void* const* d_in, const int* in_sizes, int n_in,
                              void* d_out, int out_size, void* d_ws, size_t ws_size,
                              hipStream_t stream) {
  const int* tok = (const int*)d_in[0];
  const int* eidx = (const int*)d_in[1];
  const int* srcp = eidx;
  const int* dstp = eidx + N_EDGES;
  const float* attr = (const float*)d_in[2];
  const float* emb = (const float*)d_in[4];
  const float* w_proj = (const float*)d_in[5];
  const float* b_proj = (const float*)d_in[6];
  const float *ws_[3], *bs_[3], *wm_[3], *bm_[3], *we_[3], *be_[3];
  for (int i = 0; i < 3; ++i) {
    ws_[i] = (const float*)d_in[7 + 6 * i];
    bs_[i] = (const float*)d_in[8 + 6 * i];
    wm_[i] = (const float*)d_in[9 + 6 * i];
    bm_[i] = (const float*)d_in[10 + 6 * i];
    we_[i] = (const float*)d_in[11 + 6 * i];
    be_[i] = (const float*)d_in[12 + 6 * i];
  }
  float* out = (float*)d_out;

  // ---- workspace layout (bytes) ----
  char* base = (char*)d_ws;
  size_t off = 0;
  int* ctrl = (int*)(base + off); off += 256;
  const size_t MB = 100096;  // mask bytes, padded
  u8* m0 = (u8*)(base + off); off += MB;
  u8* m1 = (u8*)(base + off); off += MB;
  u8* m2 = (u8*)(base + off); off += MB;
  size_t zero_bytes = off;                       // ctrl + all masks, contiguous
  int* emap = (int*)(base + off); off += (size_t)N_EDGES * 4;
  int* E1 = (int*)(base + off); off += (size_t)CAP1 * 4;
  int* E2 = (int*)(base + off); off += (size_t)CAP2 * 4;
  int* E3 = (int*)(base + off); off += (size_t)CAP3 * 4;
  int* L0 = (int*)(base + off); off += (size_t)N_NODES * 4;
  int* L1 = (int*)(base + off); off += (size_t)N_NODES * 4;
  int* L2 = (int*)(base + off); off += (size_t)N_NODES * 4;
  off = (off + 511) & ~(size_t)511;
  float* xA = (float*)(base + off); off += (size_t)N_NODES * D * 4;
  float* xB = (float*)(base + off); off += (size_t)N_NODES * D * 4;
  u16* ea = (u16*)(base + off); off += (size_t)CAP1 * D * 2;

  // reset counters + masks (ws is NOT re-poisoned between replays)
  hipMemsetAsync(d_ws, 0, zero_bytes, stream);

  dim3 B(256);
  const int EG = (N_EDGES + 255) / 256;   // 2344
  const int NG = (N_NODES + 255) / 256;   // 391
  const int LG = 1024;                    // grid-stride list kernels
  const int LG2 = 2048;

  // dependency-cone construction
  k_mark_masters<<<1, B, 0, stream>>>(m2);
  k_scan3<<<EG, B, 0, stream>>>(srcp, dstp, m2, E3, ctrl);
  k_scan2<<<EG, B, 0, stream>>>(srcp, dstp, m2, m1, E2, ctrl);
  k_or_mask<<<NG, B, 0, stream>>>(m1, m2);
  k_scan1<<<EG, B, 0, stream>>>(srcp, dstp, m1, m0, E1, emap, ctrl);
  k_or_mask<<<NG, B, 0, stream>>>(m0, m1);
  k_compact<<<NG, B, 0, stream>>>(m0, L0, ctrl, C_L0);
  k_compact<<<NG, B, 0, stream>>>(m1, L1, ctrl, C_L1);
  k_compact<<<NG, B, 0, stream>>>(m2, L2, ctrl, C_L2);

  // inputs of the cone
  k_embed_l<<<LG2, B, 0, stream>>>(tok, emb, xA, L0, ctrl, C_L0);
  k_proj_l<<<LG2, B, 0, stream>>>(attr, w_proj, b_proj, ea, E1, ctrl);

  // layer 1: x0(xA) -> x1(xB) on S1; ea0 -> ea1 on E2 (in place, after msg reads)
  k_self_l<<<LG, B, 0, stream>>>(xA, ws_[0], bs_[0], xB, L1, ctrl, C_L1);
  k_msg_l<<<LG2, B, 0, stream>>>(xA, ea, srcp, dstp, emap, wm_[0], bm_[0], xB, E1, ctrl, C_E1);
  k_edge_l<<<LG, B, 0, stream>>>(xA, ea, srcp, dstp, emap, we_[0], be_[0], E2, ctrl, C_E2);
  k_relu_l<<<LG, B, 0, stream>>>(xB, L1, ctrl, C_L1);

  // layer 2: x1(xB) -> x2(xA) on S2; ea1 -> ea2 on E3 (in place, after msg reads)
  k_self_l<<<LG, B, 0, stream>>>(xB, ws_[1], bs_[1], xA, L2, ctrl, C_L2);
  k_msg_l<<<LG, B, 0, stream>>>(xB, ea, srcp, dstp, emap, wm_[1], bm_[1], xA, E2, ctrl, C_E2);
  k_edge_l<<<LG, B, 0, stream>>>(xB, ea, srcp, dstp, emap, we_[1], be_[1], E3, ctrl, C_E3);
  k_relu_l<<<LG, B, 0, stream>>>(xA, L2, ctrl, C_L2);

  // layer 3: only masters; e_out discarded
  k_self3<<<13, B, 0, stream>>>(xA, ws_[2], bs_[2], out);
  k_msg3<<<LG, B, 0, stream>>>(xA, ea, srcp, dstp, emap, wm_[2], bm_[2], out, E3, ctrl);
}

// Round 3
// 258.534 us; speedup vs baseline: 51.7231x; 1.9761x over previous
//
#include <hip/hip_runtime.h>

typedef unsigned short u16;
typedef unsigned int u32;
typedef unsigned char u8;

#define N_NODES 100000
#define N_EDGES 600000
#define D 128
#define NPG 1000
#define NGRAPH 100

#define CAP_SLOTS 65536   // CSR slots = edges with dst in S1 (expected ~29.4k)
#define CAP_L1    16384   // S1 nodes (expected ~4.9k)
#define CAP_L2    4096    // S2 nodes (expected ~700)
#define CAP_E2    16384   // edges with dst in S2 (expected ~4.2k)
#define CAP_E3    4096    // edges into masters (expected ~600)

// ctrl slots
#define C_SLOT 0
#define C_L1   1
#define C_L2   2
#define C_E2   3
#define C_E3   4

__device__ __forceinline__ float bf2f(u16 u) {
  return __uint_as_float(((u32)u) << 16);
}
__device__ __forceinline__ u16 f2bf(float f) {
  u32 u = __float_as_uint(f);
  u32 r = (u + 0x7FFFu + ((u >> 16) & 1u)) >> 16;  // RNE
  return (u16)r;
}
__device__ __forceinline__ void fma4(float4& acc, float a, const float4 w) {
  acc.x = fmaf(a, w.x, acc.x);
  acc.y = fmaf(a, w.y, acc.y);
  acc.z = fmaf(a, w.z, acc.z);
  acc.w = fmaf(a, w.w, acc.w);
}
__device__ __forceinline__ float4 bf4(uint2 u) {
  return make_float4(bf2f((u16)(u.x & 0xFFFFu)), bf2f((u16)(u.x >> 16)),
                     bf2f((u16)(u.y & 0xFFFFu)), bf2f((u16)(u.y >> 16)));
}
__device__ __forceinline__ void add4(float4& a, const float4 b) {
  a.x += b.x; a.y += b.y; a.z += b.z; a.w += b.w;
}
// broadcast lane `lane`'s float4 across the 32-lane group
__device__ __forceinline__ float4 shfl4(float4 v, int lane) {
  return make_float4(__shfl(v.x, lane, 32), __shfl(v.y, lane, 32),
                     __shfl(v.z, lane, 32), __shfl(v.w, lane, 32));
}

// ---------------- dependency-cone construction ----------------

__global__ __launch_bounds__(256) void k_mark(u8* __restrict__ m2) {
  int t = blockIdx.x * 256 + threadIdx.x;
  if (t < NGRAPH) m2[t * NPG] = 1;
}

// m2 |= src of edges into masters  (S2 = masters ∪ src(E3))
__global__ __launch_bounds__(256) void k_scan3(const int* __restrict__ src,
                                               const int* __restrict__ dst,
                                               u8* __restrict__ m2) {
  int e = blockIdx.x * 256 + threadIdx.x;
  if (e >= N_EDGES) return;
  if (dst[e] % NPG == 0) m2[src[e]] = 1;
}

// m1 |= src of edges into S2  (S1 = S2 ∪ src(E2); keep masks separate, test m1|m2)
__global__ __launch_bounds__(256) void k_scan2(const int* __restrict__ src,
                                               const int* __restrict__ dst,
                                               const u8* __restrict__ m2,
                                               u8* __restrict__ m1) {
  int e = blockIdx.x * 256 + threadIdx.x;
  if (e >= N_EDGES) return;
  if (m2[dst[e]]) m1[src[e]] = 1;
}

// deg[d]++ for edges with dst in S1
__global__ __launch_bounds__(256) void k_scan1(const int* __restrict__ dst,
                                               const u8* __restrict__ m1,
                                               const u8* __restrict__ m2,
                                               int* __restrict__ deg) {
  int e = blockIdx.x * 256 + threadIdx.x;
  if (e >= N_EDGES) return;
  int d = dst[e];
  if (m1[d] | m2[d]) atomicAdd(&deg[d], 1);
}

// allocate CSR segment per S1 node (order-free) + build L1/L2 lists
__global__ __launch_bounds__(256) void k_alloc(const u8* __restrict__ m1,
                                               const u8* __restrict__ m2,
                                               const int* __restrict__ deg,
                                               int* __restrict__ offn,
                                               int* __restrict__ L1,
                                               int* __restrict__ L2,
                                               int* __restrict__ ctrl) {
  int t = blockIdx.x * 256 + threadIdx.x;
  if (t >= N_NODES) return;
  if (m1[t] | m2[t]) {
    offn[t] = atomicAdd(&ctrl[C_SLOT], deg[t]);
    int a = atomicAdd(&ctrl[C_L1], 1);
    if (a < CAP_L1) L1[a] = t;
    if (m2[t]) {
      int b = atomicAdd(&ctrl[C_L2], 1);
      if (b < CAP_L2) L2[b] = t;
    }
  }
}

// scatter edges into CSR; emit E2/E3 packed lists {p, src, dst, e}
__global__ __launch_bounds__(256) void k_scatter(const int* __restrict__ src,
                                                 const int* __restrict__ dst,
                                                 const u8* __restrict__ m1,
                                                 const u8* __restrict__ m2,
                                                 const int* __restrict__ offn,
                                                 int* __restrict__ cur,
                                                 int* __restrict__ csr_src,
                                                 int* __restrict__ csr_eid,
                                                 int4* __restrict__ E2,
                                                 int4* __restrict__ E3,
                                                 int* __restrict__ ctrl) {
  int e = blockIdx.x * 256 + threadIdx.x;
  if (e >= N_EDGES) return;
  int d = dst[e];
  if (!(m1[d] | m2[d])) return;
  int s = src[e];
  int p = offn[d] + atomicAdd(&cur[d], 1);
  if (p >= CAP_SLOTS) return;
  csr_src[p] = s;
  csr_eid[p] = e;
  if (m2[d]) {
    int a = atomicAdd(&ctrl[C_E2], 1);
    if (a < CAP_E2) E2[a] = make_int4(p, s, d, e);
  }
  if (d % NPG == 0) {
    int b = atomicAdd(&ctrl[C_E3], 1);
    if (b < CAP_E3) E3[b] = make_int4(p, s, d, e);
  }
}

// ---------------- compute ----------------

// ea[p] = attr[csr_eid[p]] @ w_proj + b_proj  (bf16, no relu)
__global__ __launch_bounds__(256) void k_proj(const float* __restrict__ attr,
                                              const float* __restrict__ w,
                                              const float* __restrict__ b,
                                              const int* __restrict__ csr_eid,
                                              u16* __restrict__ ea,
                                              const int* __restrict__ ctrl) {
  int n = ctrl[C_SLOT];
  if (n > CAP_SLOTS) n = CAP_SLOTS;
  int sub = threadIdx.x >> 5, q = threadIdx.x & 31;
  const float4* w4 = (const float4*)w;
  for (int i = blockIdx.x * 8 + sub; i < n; i += gridDim.x * 8) {
    int e = csr_eid[i];
    const float* a = attr + (size_t)e * 16;
    float4 acc = ((const float4*)b)[q];
#pragma unroll
    for (int k = 0; k < 16; ++k) fma4(acc, a[k], w4[k * 32 + q]);
    u32 p0 = (u32)f2bf(acc.x) | ((u32)f2bf(acc.y) << 16);
    u32 p1 = (u32)f2bf(acc.z) | ((u32)f2bf(acc.w) << 16);
    ((uint2*)(ea + (size_t)i * D))[q] = make_uint2(p0, p1);
  }
}

// fused node update for one conv layer (aggregate-first via linearity):
// xout[n] = act( [x[n] | Σ_in x[src] | Σ_in ea] @ [ws; wm] + bs + deg*bm )
// x source: tok!=NULL -> emb[tok[.]] rows, else xin rows.
__global__ __launch_bounds__(256) void k_node(const int* __restrict__ tok,
                                              const float* __restrict__ emb,
                                              const float* __restrict__ xin,
                                              const u16* __restrict__ ea,
                                              const int* __restrict__ csr_src,
                                              const int* __restrict__ offn,
                                              const int* __restrict__ deg,
                                              const float* __restrict__ ws,
                                              const float* __restrict__ bs,
                                              const float* __restrict__ wm,
                                              const float* __restrict__ bm,
                                              const int* __restrict__ L,
                                              const int* __restrict__ ctrl, int slot,
                                              float* __restrict__ xout, int relu) {
  int n_ = ctrl[slot];
  int sub = threadIdx.x >> 5, q = threadIdx.x & 31;
  const float4* wsa = (const float4*)ws;
  const float4* wmb = (const float4*)wm;
  for (int i = blockIdx.x * 8 + sub; i < n_; i += gridDim.x * 8) {
    int n = L[i];
    int o = offn[n], dg = deg[n];
    float4 sx = make_float4(0.f, 0.f, 0.f, 0.f);
    float4 se = make_float4(0.f, 0.f, 0.f, 0.f);
    for (int p = o; p < o + dg; ++p) {
      int s = csr_src[p];
      const float* row = tok ? (emb + (size_t)tok[s] * D) : (xin + (size_t)s * D);
      add4(sx, ((const float4*)row)[q]);
      add4(se, bf4(((const uint2*)(ea + (size_t)p * D))[q]));
    }
    const float* rown = tok ? (emb + (size_t)tok[n] * D) : (xin + (size_t)n * D);
    float4 xn = ((const float4*)rown)[q];
    float4 acc = ((const float4*)bs)[q];
#pragma unroll 4
    for (int k4 = 0; k4 < 32; ++k4) {   // rows 0..127: x[n] @ ws
      float4 xv = shfl4(xn, k4);
      fma4(acc, xv.x, wsa[(k4 * 4 + 0) * 32 + q]);
      fma4(acc, xv.y, wsa[(k4 * 4 + 1) * 32 + q]);
      fma4(acc, xv.z, wsa[(k4 * 4 + 2) * 32 + q]);
      fma4(acc, xv.w, wsa[(k4 * 4 + 3) * 32 + q]);
    }
#pragma unroll 4
    for (int k4 = 0; k4 < 32; ++k4) {   // wm rows 0..127: Σx_src
      float4 xv = shfl4(sx, k4);
      fma4(acc, xv.x, wmb[(k4 * 4 + 0) * 32 + q]);
      fma4(acc, xv.y, wmb[(k4 * 4 + 1) * 32 + q]);
      fma4(acc, xv.z, wmb[(k4 * 4 + 2) * 32 + q]);
      fma4(acc, xv.w, wmb[(k4 * 4 + 3) * 32 + q]);
    }
#pragma unroll 4
    for (int k4 = 0; k4 < 32; ++k4) {   // wm rows 128..255: Σea
      float4 xv = shfl4(se, k4);
      fma4(acc, xv.x, wmb[(D + k4 * 4 + 0) * 32 + q]);
      fma4(acc, xv.y, wmb[(D + k4 * 4 + 1) * 32 + q]);
      fma4(acc, xv.z, wmb[(D + k4 * 4 + 2) * 32 + q]);
      fma4(acc, xv.w, wmb[(D + k4 * 4 + 3) * 32 + q]);
    }
    float4 bmv = ((const float4*)bm)[q];
    float dgf = (float)dg;
    acc.x = fmaf(dgf, bmv.x, acc.x);
    acc.y = fmaf(dgf, bmv.y, acc.y);
    acc.z = fmaf(dgf, bmv.z, acc.z);
    acc.w = fmaf(dgf, bmv.w, acc.w);
    if (relu) {
      acc.x = fmaxf(acc.x, 0.f);
      acc.y = fmaxf(acc.y, 0.f);
      acc.z = fmaxf(acc.z, 0.f);
      acc.w = fmaxf(acc.w, 0.f);
    }
    ((float4*)(xout + (size_t)n * D))[q] = acc;
  }
}

// ea[p] = relu([x[dst] | x[src] | ea[p]] @ we + be) over a packed edge list
__global__ __launch_bounds__(256) void k_edge(const int* __restrict__ tok,
                                              const float* __restrict__ emb,
                                              const float* __restrict__ xin,
                                              u16* __restrict__ ea,
                                              const int4* __restrict__ EL,
                                              const int* __restrict__ ctrl, int slot,
                                              const float* __restrict__ we,
                                              const float* __restrict__ be) {
  int n_ = ctrl[slot];
  int sub = threadIdx.x >> 5, q = threadIdx.x & 31;
  const float4* w4 = (const float4*)we;
  for (int i = blockIdx.x * 8 + sub; i < n_; i += gridDim.x * 8) {
    int4 t = EL[i];
    int p = t.x, s = t.y, d = t.z;
    const float* rowd = tok ? (emb + (size_t)tok[d] * D) : (xin + (size_t)d * D);
    const float* rows = tok ? (emb + (size_t)tok[s] * D) : (xin + (size_t)s * D);
    float4 xi = ((const float4*)rowd)[q];
    float4 xj = ((const float4*)rows)[q];
    float4 ev = bf4(((const uint2*)(ea + (size_t)p * D))[q]);
    float4 acc = ((const float4*)be)[q];
#pragma unroll 4
    for (int k4 = 0; k4 < 32; ++k4) {
      float4 xv = shfl4(xi, k4);
      fma4(acc, xv.x, w4[(k4 * 4 + 0) * 32 + q]);
      fma4(acc, xv.y, w4[(k4 * 4 + 1) * 32 + q]);
      fma4(acc, xv.z, w4[(k4 * 4 + 2) * 32 + q]);
      fma4(acc, xv.w, w4[(k4 * 4 + 3) * 32 + q]);
    }
#pragma unroll 4
    for (int k4 = 0; k4 < 32; ++k4) {
      float4 xv = shfl4(xj, k4);
      fma4(acc, xv.x, w4[(D + k4 * 4 + 0) * 32 + q]);
      fma4(acc, xv.y, w4[(D + k4 * 4 + 1) * 32 + q]);
      fma4(acc, xv.z, w4[(D + k4 * 4 + 2) * 32 + q]);
      fma4(acc, xv.w, w4[(D + k4 * 4 + 3) * 32 + q]);
    }
#pragma unroll 4
    for (int k4 = 0; k4 < 32; ++k4) {
      float4 xv = shfl4(ev, k4);
      fma4(acc, xv.x, w4[(2 * D + k4 * 4 + 0) * 32 + q]);
      fma4(acc, xv.y, w4[(2 * D + k4 * 4 + 1) * 32 + q]);
      fma4(acc, xv.z, w4[(2 * D + k4 * 4 + 2) * 32 + q]);
      fma4(acc, xv.w, w4[(2 * D + k4 * 4 + 3) * 32 + q]);
    }
    acc.x = fmaxf(acc.x, 0.f);
    acc.y = fmaxf(acc.y, 0.f);
    acc.z = fmaxf(acc.z, 0.f);
    acc.w = fmaxf(acc.w, 0.f);
    u32 p0 = (u32)f2bf(acc.x) | ((u32)f2bf(acc.y) << 16);
    u32 p1 = (u32)f2bf(acc.z) | ((u32)f2bf(acc.w) << 16);
    ((uint2*)(ea + (size_t)p * D))[q] = make_uint2(p0, p1);
  }
}

// layer 3 on masters only: out[g] = [x2[g*NPG] | Σx2[src] | Σea2] @ [ws3;wm3] + bs3 + deg*bm3
__global__ __launch_bounds__(256) void k_out(const float* __restrict__ x2,
                                             const u16* __restrict__ ea,
                                             const int* __restrict__ csr_src,
                                             const int* __restrict__ offn,
                                             const int* __restrict__ deg,
                                             const float* __restrict__ ws,
                                             const float* __restrict__ bs,
                                             const float* __restrict__ wm,
                                             const float* __restrict__ bm,
                                             float* __restrict__ out) {
  int t = blockIdx.x * 256 + threadIdx.x;
  int g = t >> 5;
  if (g >= NGRAPH) return;
  int q = t & 31;
  int n = g * NPG;
  int o = offn[n], dg = deg[n];
  float4 sx = make_float4(0.f, 0.f, 0.f, 0.f);
  float4 se = make_float4(0.f, 0.f, 0.f, 0.f);
  for (int p = o; p < o + dg; ++p) {
    int s = csr_src[p];
    add4(sx, ((const float4*)(x2 + (size_t)s * D))[q]);
    add4(se, bf4(((const uint2*)(ea + (size_t)p * D))[q]));
  }
  float4 xn = ((const float4*)(x2 + (size_t)n * D))[q];
  float4 acc = ((const float4*)bs)[q];
  const float4* wsa = (const float4*)ws;
  const float4* wmb = (const float4*)wm;
#pragma unroll 4
  for (int k4 = 0; k4 < 32; ++k4) {
    float4 xv = shfl4(xn, k4);
    fma4(acc, xv.x, wsa[(k4 * 4 + 0) * 32 + q]);
    fma4(acc, xv.y, wsa[(k4 * 4 + 1) * 32 + q]);
    fma4(acc, xv.z, wsa[(k4 * 4 + 2) * 32 + q]);
    fma4(acc, xv.w, wsa[(k4 * 4 + 3) * 32 + q]);
  }
#pragma unroll 4
  for (int k4 = 0; k4 < 32; ++k4) {
    float4 xv = shfl4(sx, k4);
    fma4(acc, xv.x, wmb[(k4 * 4 + 0) * 32 + q]);
    fma4(acc, xv.y, wmb[(k4 * 4 + 1) * 32 + q]);
    fma4(acc, xv.z, wmb[(k4 * 4 + 2) * 32 + q]);
    fma4(acc, xv.w, wmb[(k4 * 4 + 3) * 32 + q]);
  }
#pragma unroll 4
  for (int k4 = 0; k4 < 32; ++k4) {
    float4 xv = shfl4(se, k4);
    fma4(acc, xv.x, wmb[(D + k4 * 4 + 0) * 32 + q]);
    fma4(acc, xv.y, wmb[(D + k4 * 4 + 1) * 32 + q]);
    fma4(acc, xv.z, wmb[(D + k4 * 4 + 2) * 32 + q]);
    fma4(acc, xv.w, wmb[(D + k4 * 4 + 3) * 32 + q]);
  }
  float4 bmv = ((const float4*)bm)[q];
  float dgf = (float)dg;
  acc.x = fmaf(dgf, bmv.x, acc.x);
  acc.y = fmaf(dgf, bmv.y, acc.y);
  acc.z = fmaf(dgf, bmv.z, acc.z);
  acc.w = fmaf(dgf, bmv.w, acc.w);
  ((float4*)(out + (size_t)g * D))[q] = acc;
}

extern "C" void kernel_launch(void* const* d_in, const int* in_sizes, int n_in,
                              void* d_out, int out_size, void* d_ws, size_t ws_size,
                              hipStream_t stream) {
  const int* tok = (const int*)d_in[0];
  const int* eidx = (const int*)d_in[1];
  const int* srcp = eidx;
  const int* dstp = eidx + N_EDGES;
  const float* attr = (const float*)d_in[2];
  const float* emb = (const float*)d_in[4];
  const float* w_proj = (const float*)d_in[5];
  const float* b_proj = (const float*)d_in[6];
  const float *ws_[3], *bs_[3], *wm_[3], *bm_[3], *we_[3], *be_[3];
  for (int i = 0; i < 3; ++i) {
    ws_[i] = (const float*)d_in[7 + 6 * i];
    bs_[i] = (const float*)d_in[8 + 6 * i];
    wm_[i] = (const float*)d_in[9 + 6 * i];
    bm_[i] = (const float*)d_in[10 + 6 * i];
    we_[i] = (const float*)d_in[11 + 6 * i];
    be_[i] = (const float*)d_in[12 + 6 * i];
  }
  float* out = (float*)d_out;

  // ---- workspace layout ----
  char* base = (char*)d_ws;
  size_t o = 0;
  auto align16 = [&]() { o = (o + 15) & ~(size_t)15; };
  int* ctrl = (int*)(base + o); o += 256;
  int* deg  = (int*)(base + o); o += (size_t)N_NODES * 4;
  int* cur  = (int*)(base + o); o += (size_t)N_NODES * 4;
  u8* m1    = (u8*)(base + o); o += 100096;
  u8* m2    = (u8*)(base + o); o += 100096;
  size_t zero_bytes = o;  // everything above must start at 0 each call
  int* offn = (int*)(base + o); o += (size_t)N_NODES * 4;
  int* csr_src = (int*)(base + o); o += (size_t)CAP_SLOTS * 4;
  int* csr_eid = (int*)(base + o); o += (size_t)CAP_SLOTS * 4;
  align16();
  int4* E2 = (int4*)(base + o); o += (size_t)CAP_E2 * 16;
  int4* E3 = (int4*)(base + o); o += (size_t)CAP_E3 * 16;
  int* L1 = (int*)(base + o); o += (size_t)CAP_L1 * 4;
  int* L2 = (int*)(base + o); o += (size_t)CAP_L2 * 4;
  o = (o + 511) & ~(size_t)511;
  float* x1 = (float*)(base + o); o += (size_t)N_NODES * D * 4;
  float* x2 = (float*)(base + o); o += (size_t)N_NODES * D * 4;
  u16* ea = (u16*)(base + o); o += (size_t)CAP_SLOTS * D * 2;

  hipMemsetAsync(d_ws, 0, zero_bytes, stream);

  dim3 B(256);
  const int EG = (N_EDGES + 255) / 256;  // 2344
  const int NG = (N_NODES + 255) / 256;  // 391

  // cone + CSR construction (int atomics only)
  k_mark<<<1, B, 0, stream>>>(m2);
  k_scan3<<<EG, B, 0, stream>>>(srcp, dstp, m2);
  k_scan2<<<EG, B, 0, stream>>>(srcp, dstp, m2, m1);
  k_scan1<<<EG, B, 0, stream>>>(dstp, m1, m2, deg);
  k_alloc<<<NG, B, 0, stream>>>(m1, m2, deg, offn, L1, L2, ctrl);
  k_scatter<<<EG, B, 0, stream>>>(srcp, dstp, m1, m2, offn, cur,
                                  csr_src, csr_eid, E2, E3, ctrl);

  // edge projection into compact CSR-ordered ea (bf16)
  k_proj<<<2048, B, 0, stream>>>(attr, w_proj, b_proj, csr_eid, ea, ctrl);

  // layer 1: x0 = emb[tok]; x1 = relu(conv1) on S1; ea1 = relu(edgeconv1) on E2
  k_node<<<1024, B, 0, stream>>>(tok, emb, nullptr, ea, csr_src, offn, deg,
                                 ws_[0], bs_[0], wm_[0], bm_[0], L1, ctrl, C_L1, x1, 1);
  k_edge<<<512, B, 0, stream>>>(tok, emb, nullptr, ea, E2, ctrl, C_E2, we_[0], be_[0]);

  // layer 2: x2 = relu(conv2) on S2 (reads x1, ea1); ea2 on E3 (reads x1, ea1)
  k_node<<<128, B, 0, stream>>>(nullptr, nullptr, x1, ea, csr_src, offn, deg,
                                ws_[1], bs_[1], wm_[1], bm_[1], L2, ctrl, C_L2, x2, 1);
  k_edge<<<128, B, 0, stream>>>(nullptr, nullptr, x1, ea, E3, ctrl, C_E3, we_[1], be_[1]);

  // layer 3: masters only, no relu, e_out discarded
  k_out<<<13, B, 0, stream>>>(x2, ea, csr_src, offn, deg,
                              ws_[2], bs_[2], wm_[2], bm_[2], out);
}